// Round 1
// baseline (239.584 us; speedup 1.0000x reference)
//
#include <hip/hip_runtime.h>
#include <hip/hip_bf16.h>
#include <float.h>
#include <math.h>

// Problem constants
#define BATCH   8192
#define NCH     45
#define SEQL    21
#define NEXP    22
#define ROWLEN  945          // NCH*SEQL
#define GOFF    7741440      // BATCH*ROWLEN, start of A_flat in d_out

#define K1_BLOCKS 1024       // 4096 waves, 2 batches each
#define K3_BLOCKS 2048       // 4 batches per block

// ---------------- K1: gating (conv -> max/avg pool -> 2x MLP -> softmax) ----------------
__global__ __launch_bounds__(256) void k1_gate(
    const float* __restrict__ x,
    const float* __restrict__ gc_w, const float* __restrict__ gc_b,
    const float* __restrict__ w1,   const float* __restrict__ b1,
    const float* __restrict__ w2,   const float* __restrict__ b2,
    float* __restrict__ gate_out,   float* __restrict__ partials)
{
    __shared__ float buf45a[4][45];
    __shared__ float buf45b[4][45];
    __shared__ float buf25a[4][25];
    __shared__ float buf25b[4][25];
    __shared__ float part[4][45];

    const int tid  = threadIdx.x;
    const int w    = tid >> 6;
    const int lane = tid & 63;
    const int waveGlobal = blockIdx.x * 4 + w;

    float acc = 0.f;   // per-lane (channel) gate accumulator over this wave's batches

    for (int iter = 0; iter < 2; ++iter) {
        const int b = waveGlobal + iter * (K1_BLOCKS * 4);
        float g = 0.f;
        if (lane < NCH) {
            // conv: temp[o] = gc_b[o] + sum_l gc_w[o,l]*x[b,lane,l]; pool over o
            float xr[SEQL];
            const float* xp = x + (size_t)b * ROWLEN + lane * SEQL;
            #pragma unroll
            for (int l = 0; l < SEQL; ++l) xr[l] = xp[l];
            float mx = -FLT_MAX, av = 0.f;
            for (int o = 0; o < SEQL; ++o) {
                float t = gc_b[o];
                #pragma unroll
                for (int l = 0; l < SEQL; ++l) t = fmaf(gc_w[o * SEQL + l], xr[l], t);
                mx = fmaxf(mx, t);
                av += t;
            }
            av *= (1.f / 21.f);
            buf45a[w][lane] = mx;
            buf45b[w][lane] = av;
        }
        __syncthreads();
        if (lane < 25) {   // layer 1 (shared weights, two inputs mx/av)
            float tm = b1[lane], ta = b1[lane];
            for (int i = 0; i < NCH; ++i) {
                const float wv = w1[lane * NCH + i];
                tm = fmaf(wv, buf45a[w][i], tm);
                ta = fmaf(wv, buf45b[w][i], ta);
            }
            buf25a[w][lane] = tanhf(tm);
            buf25b[w][lane] = tanhf(ta);
        }
        __syncthreads();
        if (lane < NCH) {  // layer 2 + combine
            float tm = b2[lane], ta = b2[lane];
            for (int j = 0; j < 25; ++j) {
                const float wv = w2[lane * 25 + j];
                tm = fmaf(wv, buf25a[w][j], tm);
                ta = fmaf(wv, buf25b[w][j], ta);
            }
            g = tanhf(tm) + tanhf(ta);
            buf45a[w][lane] = g;
        }
        __syncthreads();
        if (lane < NCH) {  // softmax over 45 channels (deterministic, same order all lanes)
            float m = -FLT_MAX;
            for (int i = 0; i < NCH; ++i) m = fmaxf(m, buf45a[w][i]);
            buf45b[w][lane] = __expf(g - m);
        }
        __syncthreads();
        if (lane < NCH) {
            float s = 0.f;
            for (int i = 0; i < NCH; ++i) s += buf45b[w][i];
            const float gt = buf45b[w][lane] / s;
            gate_out[(size_t)b * NCH + lane] = gt;
            acc += gt;
        }
        __syncthreads();   // protect LDS reuse next iteration
    }

    if (lane < NCH) part[w][lane] = acc;
    __syncthreads();
    if (tid < NCH) {
        partials[blockIdx.x * NCH + tid] =
            part[0][tid] + part[1][tid] + part[2][tid] + part[3][tid];
    }
}

// ---------------- K2: reduce partials, top-22 select+sort, expert scalars ----------------
__global__ __launch_bounds__(256) void k2_topk(
    const float* __restrict__ partials,
    const float* __restrict__ wq, const float* __restrict__ bq,
    const float* __restrict__ wk, const float* __restrict__ bk,
    const float* __restrict__ wv, const float* __restrict__ bv,
    const float* __restrict__ wo, const float* __restrict__ bo,
    float* __restrict__ escal, int* __restrict__ sel_out, int* __restrict__ c2e_out)
{
    __shared__ float red[5][45];
    __shared__ float mg[45];
    const int tid = threadIdx.x;

    if (tid < 225) {
        const int c = tid % 45, g = tid / 45;
        float s = 0.f;
        for (int p = g; p < K1_BLOCKS; p += 5) s += partials[p * 45 + c];
        red[g][c] = s;
    }
    __syncthreads();
    if (tid < 45)
        mg[tid] = red[0][tid] + red[1][tid] + red[2][tid] + red[3][tid] + red[4][tid];
    __syncthreads();

    if (tid == 0) {
        float vals[45];
        int chosen[NEXP];
        for (int i = 0; i < 45; ++i) vals[i] = mg[i];
        for (int k = 0; k < NEXP; ++k) {          // top-k: ties -> lowest index (matches lax.top_k)
            int bi = 0; float bvv = vals[0];
            for (int i = 1; i < 45; ++i)
                if (vals[i] > bvv) { bvv = vals[i]; bi = i; }
            chosen[k] = bi;
            vals[bi] = -FLT_MAX;
        }
        for (int a = 1; a < NEXP; ++a) {          // insertion sort ascending
            const int key = chosen[a];
            int p = a - 1;
            while (p >= 0 && chosen[p] > key) { chosen[p + 1] = chosen[p]; --p; }
            chosen[p + 1] = key;
        }
        for (int c = 0; c < 45; ++c) c2e_out[c] = -1;
        for (int e = 0; e < NEXP; ++e) { sel_out[e] = chosen[e]; c2e_out[chosen[e]] = e; }
    }

    if (tid < NEXP) {    // per-expert scalars (independent of sel)
        const int e = tid;
        float A = 0.f, Cc = 0.f, P = 0.f, Q = 0.f;
        for (int c = 0; c < SEQL; ++c) {
            A  = fmaf(wq[e * SEQL + c], wk[e * SEQL + c], A);
            Cc = fmaf(bq[e * SEQL + c], wk[e * SEQL + c], Cc);
            P  = fmaf(wo[e * SEQL + c], wv[e * SEQL + c], P);
            Q  = fmaf(wo[e * SEQL + c], bv[e * SEQL + c], Q);
        }
        Q += bo[e];
        escal[e] = A; escal[22 + e] = Cc; escal[44 + e] = P; escal[66 + e] = Q;
    }
}

// ---------------- K3: per-(batch,expert) softmax-avg + gated output write ----------------
__global__ __launch_bounds__(256) void k3_attn(
    const float* __restrict__ x, const float* __restrict__ gate,
    const float* __restrict__ escal, const int* __restrict__ sel,
    const int* __restrict__ c2e, float* __restrict__ out)
{
    __shared__ float xs[462];    // 22 experts x 21
    __shared__ float yA[462];
    __shared__ float gat[NEXP];
    __shared__ float sA[NEXP], sC[NEXP], sP[NEXP], sQ[NEXP];
    __shared__ int   ssel[NEXP];
    __shared__ int   sc2e[45];

    const int tid = threadIdx.x;
    if (tid < NEXP) {
        ssel[tid] = sel[tid];
        sA[tid] = escal[tid];       sC[tid] = escal[22 + tid];
        sP[tid] = escal[44 + tid];  sQ[tid] = escal[66 + tid];
    }
    if (tid < 45) sc2e[tid] = c2e[tid];
    __syncthreads();

    const int b0 = blockIdx.x * 4;
    for (int bi = 0; bi < 4; ++bi) {
        const int b = b0 + bi;
        // stage selected channels + gates
        for (int t = tid; t < 462 + NEXP; t += 256) {
            if (t < 462) {
                const int e = t / 21, l = t - e * 21;
                xs[t] = x[(size_t)b * ROWLEN + ssel[e] * SEQL + l];
            } else {
                const int e = t - 462;
                gat[e] = gate[(size_t)b * NCH + ssel[e]];
            }
        }
        __syncthreads();
        // 462 row-tasks: softmax over m of alpha*xs[m], weighted avg of xs
        for (int t = tid; t < 462; t += 256) {
            const int e = t / 21, l = t - e * 21;
            const float* xr = &xs[e * 21];
            const float alpha = fmaf(sA[e], xr[l], sC[e]);
            float m = -FLT_MAX;
            #pragma unroll
            for (int mm = 0; mm < SEQL; ++mm) m = fmaxf(m, alpha * xr[mm]);
            float den = 0.f, num = 0.f;
            #pragma unroll
            for (int mm = 0; mm < SEQL; ++mm) {
                const float wgt = __expf(fmaf(alpha, xr[mm], -m));
                den += wgt;
                num = fmaf(xr[mm], wgt, num);
            }
            const float s = num / den;
            const float y = fmaf(sP[e], s, sQ[e]);
            yA[t] = y * gat[e];
        }
        __syncthreads();
        // coalesced output write: G then A (zeros for non-selected channels)
        float* gOut = out + (size_t)b * ROWLEN;
        float* aOut = out + (size_t)GOFF + (size_t)b * ROWLEN;
        for (int j = tid; j < ROWLEN; j += 256) {
            const int c = j / 21, l = j - c * 21;
            const int e2 = sc2e[c];
            const float a = (e2 >= 0) ? yA[e2 * 21 + l] : 0.f;
            const float g = (e2 >= 0) ? a * xs[e2 * 21 + l] : 0.f;
            gOut[j] = g;
            aOut[j] = a;
        }
        __syncthreads();
    }
}

extern "C" void kernel_launch(void* const* d_in, const int* in_sizes, int n_in,
                              void* d_out, int out_size, void* d_ws, size_t ws_size,
                              hipStream_t stream)
{
    const float* x    = (const float*)d_in[0];
    const float* gc_w = (const float*)d_in[1];
    const float* gc_b = (const float*)d_in[2];
    const float* w1   = (const float*)d_in[3];
    const float* b1   = (const float*)d_in[4];
    const float* w2   = (const float*)d_in[5];
    const float* b2   = (const float*)d_in[6];
    const float* wq   = (const float*)d_in[7];
    const float* bq   = (const float*)d_in[8];
    const float* wk   = (const float*)d_in[9];
    const float* bk   = (const float*)d_in[10];
    const float* wv   = (const float*)d_in[11];
    const float* bv   = (const float*)d_in[12];
    const float* wo   = (const float*)d_in[13];
    const float* bo   = (const float*)d_in[14];

    float* ws       = (float*)d_ws;
    float* gateBuf  = ws;                       // BATCH*45 = 368640 floats
    float* partials = ws + 368640;              // 1024*45  = 46080 floats
    float* escal    = ws + 414720;              // 88 floats (A,C,P,Q per expert)
    int*   sel      = (int*)(ws + 414816);      // 22 ints
    int*   c2e      = sel + NEXP;               // 45 ints
    float* outF     = (float*)d_out;

    k1_gate<<<dim3(K1_BLOCKS), dim3(256), 0, stream>>>(x, gc_w, gc_b, w1, b1, w2, b2,
                                                       gateBuf, partials);
    k2_topk<<<dim3(1), dim3(256), 0, stream>>>(partials, wq, bq, wk, bk, wv, bv, wo, bo,
                                               escal, sel, c2e);
    k3_attn<<<dim3(K3_BLOCKS), dim3(256), 0, stream>>>(x, gateBuf, escal, sel, c2e, outF);
}

// Round 2
// 199.396 us; speedup vs baseline: 1.2016x; 1.2016x over previous
//
#include <hip/hip_runtime.h>
#include <hip/hip_bf16.h>
#include <float.h>
#include <math.h>

// Problem constants
#define BATCH   8192
#define NCH     45
#define SEQL    21
#define NEXP    22
#define ROWLEN  945          // NCH*SEQL
#define GOFF    7741440      // BATCH*ROWLEN, start of A_flat in d_out

#define K1_BLOCKS 1024       // 8 batches per block
#define K3_BLOCKS 2048       // 4 batches per block (3780 floats = 945 float4 exactly)

// ---------------- K1: gating (conv -> max/avg pool -> 2x MLP -> softmax) ----------------
__global__ __launch_bounds__(256) void k1_gate(
    const float* __restrict__ x,
    const float* __restrict__ gc_w, const float* __restrict__ gc_b,
    const float* __restrict__ w1,   const float* __restrict__ b1,
    const float* __restrict__ w2,   const float* __restrict__ b2,
    float* __restrict__ gate_out,   float* __restrict__ partials)
{
    __shared__ float xsh[8 * ROWLEN];       // 30240 B, 8 batch rows
    __shared__ float buf45a[4][45];
    __shared__ float buf45b[4][45];
    __shared__ float buf25a[4][25];
    __shared__ float buf25b[4][25];
    __shared__ float part[4][45];

    const int tid  = threadIdx.x;
    const int w    = tid >> 6;
    const int lane = tid & 63;
    const int b_base = blockIdx.x * 8;

    // ---- stage 8 consecutive batch rows, fully coalesced float4 ----
    {
        const float4* x4 = (const float4*)(x + (size_t)b_base * ROWLEN); // 30240B-aligned
        float4* xsh4 = (float4*)xsh;
        for (int q = tid; q < 1890; q += 256) xsh4[q] = x4[q];
    }
    __syncthreads();

    float acc = 0.f;   // per-lane (channel) gate accumulator over this wave's batches

    for (int iter = 0; iter < 2; ++iter) {
        const int bb = w * 2 + iter;        // local row 0..7
        const int b  = b_base + bb;
        float g = 0.f;
        if (lane < NCH) {
            // conv: temp[o] = gc_b[o] + sum_l gc_w[o,l]*x[b,lane,l]; pool over o
            float xr[SEQL];
            const float* xp = &xsh[bb * ROWLEN + lane * SEQL];  // stride-21: conflict-free
            #pragma unroll
            for (int l = 0; l < SEQL; ++l) xr[l] = xp[l];
            float mx = -FLT_MAX, av = 0.f;
            for (int o = 0; o < SEQL; ++o) {
                float t = gc_b[o];
                #pragma unroll
                for (int l = 0; l < SEQL; ++l) t = fmaf(gc_w[o * SEQL + l], xr[l], t);
                mx = fmaxf(mx, t);
                av += t;
            }
            av *= (1.f / 21.f);
            buf45a[w][lane] = mx;
            buf45b[w][lane] = av;
        }
        __syncthreads();
        if (lane < 25) {   // layer 1 (shared weights, two inputs mx/av)
            float tm = b1[lane], ta = b1[lane];
            for (int i = 0; i < NCH; ++i) {
                const float wv = w1[lane * NCH + i];
                tm = fmaf(wv, buf45a[w][i], tm);
                ta = fmaf(wv, buf45b[w][i], ta);
            }
            buf25a[w][lane] = tanhf(tm);
            buf25b[w][lane] = tanhf(ta);
        }
        __syncthreads();
        if (lane < NCH) {  // layer 2 + combine; exp without max (g in [-2,2], safe)
            float tm = b2[lane], ta = b2[lane];
            for (int j = 0; j < 25; ++j) {
                const float wv = w2[lane * 25 + j];
                tm = fmaf(wv, buf25a[w][j], tm);
                ta = fmaf(wv, buf25b[w][j], ta);
            }
            g = __expf(tanhf(tm) + tanhf(ta));
            buf45a[w][lane] = g;
        }
        __syncthreads();
        if (lane < NCH) {
            float s = 0.f;
            for (int i = 0; i < NCH; ++i) s += buf45a[w][i];
            const float gt = g / s;
            gate_out[(size_t)b * NCH + lane] = gt;
            acc += gt;
        }
        __syncthreads();   // protect LDS reuse next iteration
    }

    if (lane < NCH) part[w][lane] = acc;
    __syncthreads();
    if (tid < NCH) {
        partials[blockIdx.x * NCH + tid] =
            part[0][tid] + part[1][tid] + part[2][tid] + part[3][tid];
    }
}

// ---------------- K2: parallel reduce, top-22 select+sort, expert scalars ----------------
__global__ __launch_bounds__(256) void k2_topk(
    const float* __restrict__ partials,
    const float* __restrict__ wq, const float* __restrict__ bq,
    const float* __restrict__ wk, const float* __restrict__ bk,
    const float* __restrict__ wv, const float* __restrict__ bv,
    const float* __restrict__ wo, const float* __restrict__ bo,
    float* __restrict__ escal, int* __restrict__ sel_out)
{
    __shared__ float wred[4][45];
    __shared__ float mg[45];
    const int tid = threadIdx.x;

    // each thread sums 4 consecutive rows (180 contiguous floats -> dwordx4,
    // 45 independent accumulator chains; all 1024 rows covered by 256 threads)
    float s[45];
    {
        const float* rp = partials + tid * 180;
        #pragma unroll
        for (int c = 0; c < 45; ++c)
            s[c] = (rp[c] + rp[45 + c]) + (rp[90 + c] + rp[135 + c]);
    }
    // butterfly reduce across the 64-lane wave
    #pragma unroll
    for (int off = 32; off > 0; off >>= 1) {
        #pragma unroll
        for (int c = 0; c < 45; ++c) s[c] += __shfl_xor(s[c], off, 64);
    }
    if ((tid & 63) == 0) {
        #pragma unroll
        for (int c = 0; c < 45; ++c) wred[tid >> 6][c] = s[c];
    }
    __syncthreads();
    if (tid < 45)
        mg[tid] = (wred[0][tid] + wred[1][tid]) + (wred[2][tid] + wred[3][tid]);
    __syncthreads();

    if (tid == 0) {
        float vals[45];
        int chosen[NEXP];
        for (int i = 0; i < 45; ++i) vals[i] = mg[i];
        for (int k = 0; k < NEXP; ++k) {          // top-k: ties -> lowest index
            int bi = 0; float bvv = vals[0];
            for (int i = 1; i < 45; ++i)
                if (vals[i] > bvv) { bvv = vals[i]; bi = i; }
            chosen[k] = bi;
            vals[bi] = -FLT_MAX;
        }
        for (int a = 1; a < NEXP; ++a) {          // insertion sort ascending
            const int key = chosen[a];
            int p = a - 1;
            while (p >= 0 && chosen[p] > key) { chosen[p + 1] = chosen[p]; --p; }
            chosen[p + 1] = key;
        }
        for (int e = 0; e < NEXP; ++e) sel_out[e] = chosen[e];
    }

    if (tid < NEXP) {    // per-expert scalars (independent of sel)
        const int e = tid;
        float A = 0.f, Cc = 0.f, P = 0.f, Q = 0.f;
        for (int c = 0; c < SEQL; ++c) {
            A  = fmaf(wq[e * SEQL + c], wk[e * SEQL + c], A);
            Cc = fmaf(bq[e * SEQL + c], wk[e * SEQL + c], Cc);
            P  = fmaf(wo[e * SEQL + c], wv[e * SEQL + c], P);
            Q  = fmaf(wo[e * SEQL + c], bv[e * SEQL + c], Q);
        }
        Q += bo[e];
        escal[e] = A; escal[22 + e] = Cc; escal[44 + e] = P; escal[66 + e] = Q;
    }
}

// ---------------- K3: per-(batch,expert) softmax-avg + gated output, all-float4 ----------------
__global__ __launch_bounds__(256) void k3_attn(
    const float* __restrict__ x, const float* __restrict__ gate,
    const float* __restrict__ escal, const int* __restrict__ sel,
    float* __restrict__ out)
{
    __shared__ float xsh[4 * ROWLEN];   // 15120 B: 4 batch rows of x
    __shared__ float ash[4 * ROWLEN];   // 15120 B: full A image incl. zeros
    __shared__ float gat[4][NEXP];
    __shared__ float sA[NEXP], sC[NEXP], sP[NEXP], sQ[NEXP];
    __shared__ int   ssel[NEXP];

    const int tid = threadIdx.x;
    if (tid < NEXP) {
        ssel[tid] = sel[tid];
        sA[tid] = escal[tid];       sC[tid] = escal[22 + tid];
        sP[tid] = escal[44 + tid];  sQ[tid] = escal[66 + tid];
    }

    const int b0 = blockIdx.x * 4;
    // stage 4 rows of x (945 float4, coalesced) + zero the A image
    {
        const float4* x4 = (const float4*)x + (size_t)blockIdx.x * 945;
        float4* xsh4 = (float4*)xsh;
        float4* ash4 = (float4*)ash;
        const float4 z = make_float4(0.f, 0.f, 0.f, 0.f);
        for (int q = tid; q < 945; q += 256) {
            xsh4[q] = x4[q];
            ash4[q] = z;
        }
    }
    __syncthreads();
    if (tid < 4 * NEXP) {               // gates for 4 batches x 22 selected channels
        const int bi = tid / NEXP, e = tid - bi * NEXP;
        gat[bi][e] = gate[(size_t)(b0 + bi) * NCH + ssel[e]];
    }
    __syncthreads();

    // 4*462 = 1848 row-tasks: softmax over m of alpha*xs[m] (no max-sub: |a*x|<~3)
    for (int t = tid; t < 1848; t += 256) {
        const int bi = t / 462;
        const int r  = t - bi * 462;
        const int e  = r / 21;
        const int l  = r - e * 21;
        const float* xr = &xsh[bi * ROWLEN + ssel[e] * SEQL];
        const float alpha = fmaf(sA[e], xr[l], sC[e]);
        float den = 0.f, num = 0.f;
        #pragma unroll
        for (int mm = 0; mm < SEQL; ++mm) {
            const float wgt = __expf(alpha * xr[mm]);
            den += wgt;
            num = fmaf(xr[mm], wgt, num);
        }
        const float y = fmaf(sP[e], num / den, sQ[e]);
        ash[bi * ROWLEN + ssel[e] * SEQL + l] = y * gat[bi][e];
    }
    __syncthreads();

    // coalesced float4 writes: G = A .* x, then A
    {
        const float4* xsh4 = (const float4*)xsh;
        const float4* ash4 = (const float4*)ash;
        float4* g4 = (float4*)out + (size_t)blockIdx.x * 945;
        float4* a4 = (float4*)(out + (size_t)GOFF) + (size_t)blockIdx.x * 945;
        for (int q = tid; q < 945; q += 256) {
            const float4 a = ash4[q];
            const float4 xv = xsh4[q];
            g4[q] = make_float4(a.x * xv.x, a.y * xv.y, a.z * xv.z, a.w * xv.w);
            a4[q] = a;
        }
    }
}

extern "C" void kernel_launch(void* const* d_in, const int* in_sizes, int n_in,
                              void* d_out, int out_size, void* d_ws, size_t ws_size,
                              hipStream_t stream)
{
    const float* x    = (const float*)d_in[0];
    const float* gc_w = (const float*)d_in[1];
    const float* gc_b = (const float*)d_in[2];
    const float* w1   = (const float*)d_in[3];
    const float* b1   = (const float*)d_in[4];
    const float* w2   = (const float*)d_in[5];
    const float* b2   = (const float*)d_in[6];
    const float* wq   = (const float*)d_in[7];
    const float* bq   = (const float*)d_in[8];
    const float* wk   = (const float*)d_in[9];
    const float* bk   = (const float*)d_in[10];
    const float* wv   = (const float*)d_in[11];
    const float* bv   = (const float*)d_in[12];
    const float* wo   = (const float*)d_in[13];
    const float* bo   = (const float*)d_in[14];

    float* ws       = (float*)d_ws;
    float* gateBuf  = ws;                       // BATCH*45 = 368640 floats
    float* partials = ws + 368640;              // 1024*45  = 46080 floats
    float* escal    = ws + 414720;              // 88 floats (A,C,P,Q per expert)
    int*   sel      = (int*)(ws + 414816);      // 22 ints
    float* outF     = (float*)d_out;

    k1_gate<<<dim3(K1_BLOCKS), dim3(256), 0, stream>>>(x, gc_w, gc_b, w1, b1, w2, b2,
                                                       gateBuf, partials);
    k2_topk<<<dim3(1), dim3(256), 0, stream>>>(partials, wq, bq, wk, bk, wv, bv, wo, bo,
                                               escal, sel);
    k3_attn<<<dim3(K3_BLOCKS), dim3(256), 0, stream>>>(x, gateBuf, escal, sel, outF);
}

// Round 3
// 199.013 us; speedup vs baseline: 1.2039x; 1.0019x over previous
//
#include <hip/hip_runtime.h>
#include <hip/hip_bf16.h>
#include <float.h>
#include <math.h>

// Problem constants
#define BATCH   8192
#define NCH     45
#define SEQL    21
#define NEXP    22
#define ROWLEN  945          // NCH*SEQL
#define GOFF    7741440      // BATCH*ROWLEN, start of A_flat in d_out

#define K1_BLOCKS 1024       // 8 batches per block
#define K3_BLOCKS 2048       // 4 batches per block (3780 floats = 945 float4 exactly)

__device__ __forceinline__ float fast_tanh(float v) {
    const float t = __expf(2.f * v);
    return (t - 1.f) / (t + 1.f);
}

// ---------------- K1: gating (conv -> max/avg pool -> 2x MLP -> softmax) ----------------
__global__ __launch_bounds__(256) void k1_gate(
    const float* __restrict__ x,
    const float* __restrict__ gc_w, const float* __restrict__ gc_b,
    const float* __restrict__ w1,   const float* __restrict__ b1,
    const float* __restrict__ w2,   const float* __restrict__ b2,
    float* __restrict__ gate_out,   float* __restrict__ partialsT)
{
    __shared__ float xsh[8 * ROWLEN];       // 30240 B, 8 batch rows
    __shared__ float buf45a[4][45];
    __shared__ float buf45b[4][45];
    __shared__ float buf25a[4][25];
    __shared__ float buf25b[4][25];
    __shared__ float part[4][45];

    const int tid  = threadIdx.x;
    const int w    = tid >> 6;
    const int lane = tid & 63;
    const int b_base = blockIdx.x * 8;

    // ---- stage 8 consecutive batch rows, fully coalesced float4 ----
    {
        const float4* x4 = (const float4*)(x + (size_t)b_base * ROWLEN); // 30240B-aligned
        float4* xsh4 = (float4*)xsh;
        for (int q = tid; q < 1890; q += 256) xsh4[q] = x4[q];
    }
    __syncthreads();

    float acc = 0.f;   // per-lane (channel) gate accumulator over this wave's batches

    for (int iter = 0; iter < 2; ++iter) {
        const int bb = w * 2 + iter;        // local row 0..7
        const int b  = b_base + bb;
        float g = 0.f;
        if (lane < NCH) {
            // conv: temp[o] = gc_b[o] + sum_l gc_w[o,l]*x[b,lane,l]; pool over o
            float xr[SEQL];
            const float* xp = &xsh[bb * ROWLEN + lane * SEQL];  // stride-21: conflict-free
            #pragma unroll
            for (int l = 0; l < SEQL; ++l) xr[l] = xp[l];
            float mx = -FLT_MAX, av = 0.f;
            for (int o = 0; o < SEQL; ++o) {
                float t = gc_b[o];
                #pragma unroll
                for (int l = 0; l < SEQL; ++l) t = fmaf(gc_w[o * SEQL + l], xr[l], t);
                mx = fmaxf(mx, t);
                av += t;
            }
            av *= (1.f / 21.f);
            buf45a[w][lane] = mx;
            buf45b[w][lane] = av;
        }
        __syncthreads();
        if (lane < 25) {   // layer 1 (shared weights, two inputs mx/av)
            float tm = b1[lane], ta = b1[lane];
            for (int i = 0; i < NCH; ++i) {
                const float wv = w1[lane * NCH + i];
                tm = fmaf(wv, buf45a[w][i], tm);
                ta = fmaf(wv, buf45b[w][i], ta);
            }
            buf25a[w][lane] = fast_tanh(tm);
            buf25b[w][lane] = fast_tanh(ta);
        }
        __syncthreads();
        if (lane < NCH) {  // layer 2 + combine; exp without max (g in [-2,2], safe)
            float tm = b2[lane], ta = b2[lane];
            for (int j = 0; j < 25; ++j) {
                const float wv = w2[lane * 25 + j];
                tm = fmaf(wv, buf25a[w][j], tm);
                ta = fmaf(wv, buf25b[w][j], ta);
            }
            g = __expf(fast_tanh(tm) + fast_tanh(ta));
            buf45a[w][lane] = g;
        }
        __syncthreads();
        if (lane < NCH) {
            float s = 0.f;
            for (int i = 0; i < NCH; ++i) s += buf45a[w][i];
            const float gt = g / s;
            gate_out[(size_t)b * NCH + lane] = gt;
            acc += gt;
        }
        __syncthreads();   // protect LDS reuse next iteration
    }

    if (lane < NCH) part[w][lane] = acc;
    __syncthreads();
    if (tid < NCH) {
        // transposed: channel-major so K2 reads lane-consecutive (coalesced)
        partialsT[tid * K1_BLOCKS + blockIdx.x] =
            part[0][tid] + part[1][tid] + part[2][tid] + part[3][tid];
    }
}

// ---------------- K2: coalesced reduce, top-22 select+sort, expert scalars ----------------
__global__ __launch_bounds__(256) void k2_topk(
    const float* __restrict__ partialsT,
    const float* __restrict__ wq, const float* __restrict__ bq,
    const float* __restrict__ wk, const float* __restrict__ bk,
    const float* __restrict__ wv, const float* __restrict__ bv,
    const float* __restrict__ wo, const float* __restrict__ bo,
    float* __restrict__ escal, int* __restrict__ sel_out)
{
    __shared__ float wred[4][45];
    __shared__ float mg[45];
    const int tid = threadIdx.x;

    // partialsT layout: [c][1024]; lane-consecutive loads -> fully coalesced
    float s[45];
    #pragma unroll
    for (int c = 0; c < 45; ++c) {
        const float* col = partialsT + c * K1_BLOCKS + tid;
        s[c] = (col[0] + col[256]) + (col[512] + col[768]);
    }
    // butterfly reduce across the 64-lane wave
    #pragma unroll
    for (int off = 32; off > 0; off >>= 1) {
        #pragma unroll
        for (int c = 0; c < 45; ++c) s[c] += __shfl_xor(s[c], off, 64);
    }
    if ((tid & 63) == 0) {
        #pragma unroll
        for (int c = 0; c < 45; ++c) wred[tid >> 6][c] = s[c];
    }
    __syncthreads();
    if (tid < 45)
        mg[tid] = (wred[0][tid] + wred[1][tid]) + (wred[2][tid] + wred[3][tid]);
    __syncthreads();

    if (tid == 0) {
        float vals[45];
        int chosen[NEXP];
        for (int i = 0; i < 45; ++i) vals[i] = mg[i];
        for (int k = 0; k < NEXP; ++k) {          // top-k: ties -> lowest index
            int bi = 0; float bvv = vals[0];
            for (int i = 1; i < 45; ++i)
                if (vals[i] > bvv) { bvv = vals[i]; bi = i; }
            chosen[k] = bi;
            vals[bi] = -FLT_MAX;
        }
        for (int a = 1; a < NEXP; ++a) {          // insertion sort ascending
            const int key = chosen[a];
            int p = a - 1;
            while (p >= 0 && chosen[p] > key) { chosen[p + 1] = chosen[p]; --p; }
            chosen[p + 1] = key;
        }
        for (int e = 0; e < NEXP; ++e) sel_out[e] = chosen[e];
    }

    if (tid < NEXP) {    // per-expert scalars (independent of sel)
        const int e = tid;
        float A = 0.f, Cc = 0.f, P = 0.f, Q = 0.f;
        for (int c = 0; c < SEQL; ++c) {
            A  = fmaf(wq[e * SEQL + c], wk[e * SEQL + c], A);
            Cc = fmaf(bq[e * SEQL + c], wk[e * SEQL + c], Cc);
            P  = fmaf(wo[e * SEQL + c], wv[e * SEQL + c], P);
            Q  = fmaf(wo[e * SEQL + c], bv[e * SEQL + c], Q);
        }
        Q += bo[e];
        escal[e] = A; escal[22 + e] = Cc; escal[44 + e] = P; escal[66 + e] = Q;
    }
}

// ---------------- K3: per-(batch,expert) softmax-avg + gated output, all-float4 ----------------
__global__ __launch_bounds__(256) void k3_attn(
    const float* __restrict__ x, const float* __restrict__ gate,
    const float* __restrict__ escal, const int* __restrict__ sel,
    float* __restrict__ out)
{
    __shared__ float xsh[4 * ROWLEN];   // 15120 B: 4 batch rows of x
    __shared__ float ash[4 * ROWLEN];   // 15120 B: full A image incl. zeros
    __shared__ float gat[4][NEXP];
    __shared__ float sA[NEXP], sC[NEXP], sP[NEXP], sQ[NEXP];
    __shared__ int   ssel[NEXP];

    const int tid = threadIdx.x;
    if (tid < NEXP) {
        ssel[tid] = sel[tid];
        sA[tid] = escal[tid];       sC[tid] = escal[22 + tid];
        sP[tid] = escal[44 + tid];  sQ[tid] = escal[66 + tid];
    }

    const int b0 = blockIdx.x * 4;
    // stage 4 rows of x (945 float4, coalesced) + zero the A image
    {
        const float4* x4 = (const float4*)x + (size_t)blockIdx.x * 945;
        float4* xsh4 = (float4*)xsh;
        float4* ash4 = (float4*)ash;
        const float4 z = make_float4(0.f, 0.f, 0.f, 0.f);
        for (int q = tid; q < 945; q += 256) {
            xsh4[q] = x4[q];
            ash4[q] = z;
        }
    }
    __syncthreads();
    if (tid < 4 * NEXP) {               // gates for 4 batches x 22 selected channels
        const int bi = tid / NEXP, e = tid - bi * NEXP;
        gat[bi][e] = gate[(size_t)(b0 + bi) * NCH + ssel[e]];
    }
    __syncthreads();

    // 4*462 = 1848 row-tasks: softmax over m of alpha*xs[m] (no max-sub: |a*x|<~3)
    for (int t = tid; t < 1848; t += 256) {
        const int bi = t / 462;
        const int r  = t - bi * 462;
        const int e  = r / 21;
        const int l  = r - e * 21;
        const float* xr = &xsh[bi * ROWLEN + ssel[e] * SEQL];
        const float alpha = fmaf(sA[e], xr[l], sC[e]);
        float den = 0.f, num = 0.f;
        #pragma unroll
        for (int mm = 0; mm < SEQL; ++mm) {
            const float wgt = __expf(alpha * xr[mm]);
            den += wgt;
            num = fmaf(xr[mm], wgt, num);
        }
        const float y = fmaf(sP[e], num / den, sQ[e]);
        ash[bi * ROWLEN + ssel[e] * SEQL + l] = y * gat[bi][e];
    }
    __syncthreads();

    // coalesced float4 writes: G = A .* x, then A
    {
        const float4* xsh4 = (const float4*)xsh;
        const float4* ash4 = (const float4*)ash;
        float4* g4 = (float4*)out + (size_t)blockIdx.x * 945;
        float4* a4 = (float4*)(out + (size_t)GOFF) + (size_t)blockIdx.x * 945;
        for (int q = tid; q < 945; q += 256) {
            const float4 a = ash4[q];
            const float4 xv = xsh4[q];
            g4[q] = make_float4(a.x * xv.x, a.y * xv.y, a.z * xv.z, a.w * xv.w);
            a4[q] = a;
        }
    }
}

extern "C" void kernel_launch(void* const* d_in, const int* in_sizes, int n_in,
                              void* d_out, int out_size, void* d_ws, size_t ws_size,
                              hipStream_t stream)
{
    const float* x    = (const float*)d_in[0];
    const float* gc_w = (const float*)d_in[1];
    const float* gc_b = (const float*)d_in[2];
    const float* w1   = (const float*)d_in[3];
    const float* b1   = (const float*)d_in[4];
    const float* w2   = (const float*)d_in[5];
    const float* b2   = (const float*)d_in[6];
    const float* wq   = (const float*)d_in[7];
    const float* bq   = (const float*)d_in[8];
    const float* wk   = (const float*)d_in[9];
    const float* bk   = (const float*)d_in[10];
    const float* wv   = (const float*)d_in[11];
    const float* bv   = (const float*)d_in[12];
    const float* wo   = (const float*)d_in[13];
    const float* bo   = (const float*)d_in[14];

    float* ws        = (float*)d_ws;
    float* gateBuf   = ws;                       // BATCH*45 = 368640 floats
    float* partialsT = ws + 368640;              // 45*1024  = 46080 floats (channel-major)
    float* escal     = ws + 414720;              // 88 floats (A,C,P,Q per expert)
    int*   sel       = (int*)(ws + 414816);      // 22 ints
    float* outF      = (float*)d_out;

    k1_gate<<<dim3(K1_BLOCKS), dim3(256), 0, stream>>>(x, gc_w, gc_b, w1, b1, w2, b2,
                                                       gateBuf, partialsT);
    k2_topk<<<dim3(1), dim3(256), 0, stream>>>(partialsT, wq, bq, wk, bk, wv, bv, wo, bo,
                                               escal, sel);
    k3_attn<<<dim3(K3_BLOCKS), dim3(256), 0, stream>>>(x, gateBuf, escal, sel, outF);
}

// Round 4
// 155.386 us; speedup vs baseline: 1.5419x; 1.2808x over previous
//
#include <hip/hip_runtime.h>
#include <hip/hip_bf16.h>
#include <float.h>
#include <math.h>

// Problem constants
#define BATCH   8192
#define NCH     45
#define SEQL    21
#define NEXP    22
#define ROWLEN  945          // NCH*SEQL
#define GOFF    7741440      // BATCH*ROWLEN, start of A_flat in d_out

#define K1_BLOCKS 1024       // 8 batches per block
#define K3_BLOCKS 2048       // 4 batches per block (3780 floats = 945 float4 exactly)

__device__ __forceinline__ float fast_tanh(float v) {
    const float t = __expf(2.f * v);
    return (t - 1.f) / (t + 1.f);
}

// ---------------- K1: gating (conv -> max/avg pool -> 2x MLP -> softmax) ----------------
__global__ __launch_bounds__(256) void k1_gate(
    const float* __restrict__ x,
    const float* __restrict__ gc_w, const float* __restrict__ gc_b,
    const float* __restrict__ w1,   const float* __restrict__ b1,
    const float* __restrict__ w2,   const float* __restrict__ b2,
    float* __restrict__ gate_out,   float* __restrict__ partialsT)
{
    __shared__ float xsh[8 * ROWLEN];       // 30240 B, 8 batch rows
    __shared__ float buf45a[4][45];
    __shared__ float buf45b[4][45];
    __shared__ float buf25a[4][25];
    __shared__ float buf25b[4][25];
    __shared__ float part[4][45];

    const int tid  = threadIdx.x;
    const int w    = tid >> 6;
    const int lane = tid & 63;
    const int b_base = blockIdx.x * 8;

    // ---- stage 8 consecutive batch rows, fully coalesced float4 ----
    {
        const float4* x4 = (const float4*)(x + (size_t)b_base * ROWLEN); // 30240B-aligned
        float4* xsh4 = (float4*)xsh;
        for (int q = tid; q < 1890; q += 256) xsh4[q] = x4[q];
    }
    __syncthreads();

    float acc = 0.f;   // per-lane (channel) gate accumulator over this wave's batches

    for (int iter = 0; iter < 2; ++iter) {
        const int bb = w * 2 + iter;        // local row 0..7
        const int b  = b_base + bb;
        float g = 0.f;
        if (lane < NCH) {
            // conv: temp[o] = gc_b[o] + sum_l gc_w[o,l]*x[b,lane,l]; pool over o
            float xr[SEQL];
            const float* xp = &xsh[bb * ROWLEN + lane * SEQL];  // stride-21: <=2-way, free
            #pragma unroll
            for (int l = 0; l < SEQL; ++l) xr[l] = xp[l];
            float mx = -FLT_MAX, av = 0.f;
            for (int o = 0; o < SEQL; ++o) {
                float t = gc_b[o];
                #pragma unroll
                for (int l = 0; l < SEQL; ++l) t = fmaf(gc_w[o * SEQL + l], xr[l], t);
                mx = fmaxf(mx, t);
                av += t;
            }
            av *= (1.f / 21.f);
            buf45a[w][lane] = mx;
            buf45b[w][lane] = av;
        }
        __syncthreads();
        if (lane < 25) {   // layer 1 (shared weights, two inputs mx/av)
            float tm = b1[lane], ta = b1[lane];
            for (int i = 0; i < NCH; ++i) {
                const float wv = w1[lane * NCH + i];
                tm = fmaf(wv, buf45a[w][i], tm);
                ta = fmaf(wv, buf45b[w][i], ta);
            }
            buf25a[w][lane] = fast_tanh(tm);
            buf25b[w][lane] = fast_tanh(ta);
        }
        __syncthreads();
        if (lane < NCH) {  // layer 2 + combine; exp without max (g in [-2,2], safe)
            float tm = b2[lane], ta = b2[lane];
            for (int j = 0; j < 25; ++j) {
                const float wv = w2[lane * 25 + j];
                tm = fmaf(wv, buf25a[w][j], tm);
                ta = fmaf(wv, buf25b[w][j], ta);
            }
            g = __expf(fast_tanh(tm) + fast_tanh(ta));
            buf45a[w][lane] = g;
        }
        __syncthreads();
        if (lane < NCH) {
            float s = 0.f;
            for (int i = 0; i < NCH; ++i) s += buf45a[w][i];
            const float gt = g / s;
            gate_out[(size_t)b * NCH + lane] = gt;
            acc += gt;
        }
        __syncthreads();   // protect LDS reuse next iteration
    }

    if (lane < NCH) part[w][lane] = acc;
    __syncthreads();
    if (tid < NCH) {
        // transposed: channel-major so K2 block c reads a contiguous 4KB row
        partialsT[tid * K1_BLOCKS + blockIdx.x] =
            part[0][tid] + part[1][tid] + part[2][tid] + part[3][tid];
    }
}

// ---------------- K2: 46 blocks — per-channel reduce (0..44) + expert scalars (45) -------
__global__ __launch_bounds__(256) void k2_reduce(
    const float* __restrict__ partialsT,
    const float* __restrict__ wq, const float* __restrict__ bq,
    const float* __restrict__ wk, const float* __restrict__ bk,
    const float* __restrict__ wv, const float* __restrict__ bv,
    const float* __restrict__ wo, const float* __restrict__ bo,
    float* __restrict__ mg, float* __restrict__ escal)
{
    const int tid = threadIdx.x;
    const int c   = blockIdx.x;

    if (c < NCH) {
        // 256 threads x one float4 = all 1024 partials of channel c (contiguous)
        __shared__ float wsum[4];
        const float4 v = ((const float4*)(partialsT + c * K1_BLOCKS))[tid];
        float s = (v.x + v.y) + (v.z + v.w);
        #pragma unroll
        for (int off = 32; off > 0; off >>= 1) s += __shfl_xor(s, off, 64);
        if ((tid & 63) == 0) wsum[tid >> 6] = s;
        __syncthreads();
        if (tid == 0) mg[c] = (wsum[0] + wsum[1]) + (wsum[2] + wsum[3]);
    } else {
        if (tid < NEXP) {    // per-expert scalars (independent of selection)
            const int e = tid;
            float A = 0.f, Cc = 0.f, P = 0.f, Q = 0.f;
            for (int i = 0; i < SEQL; ++i) {
                A  = fmaf(wq[e * SEQL + i], wk[e * SEQL + i], A);
                Cc = fmaf(bq[e * SEQL + i], wk[e * SEQL + i], Cc);
                P  = fmaf(wo[e * SEQL + i], wv[e * SEQL + i], P);
                Q  = fmaf(wo[e * SEQL + i], bv[e * SEQL + i], Q);
            }
            Q += bo[e];
            escal[e] = A; escal[22 + e] = Cc; escal[44 + e] = P; escal[66 + e] = Q;
        }
    }
}

// ---------------- K3: ballot top-k preamble + softmax-avg + gated output, all-float4 -----
__global__ __launch_bounds__(256) void k3_attn(
    const float* __restrict__ x, const float* __restrict__ gate,
    const float* __restrict__ mg, const float* __restrict__ escal,
    float* __restrict__ out)
{
    __shared__ float xsh[4 * ROWLEN];   // 15120 B: 4 batch rows of x
    __shared__ float ash[4 * ROWLEN];   // 15120 B: full A image incl. zeros
    __shared__ float smg[64];
    __shared__ float gat[4][NEXP];
    __shared__ float sA[NEXP], sC[NEXP], sP[NEXP], sQ[NEXP];
    __shared__ int   ssel[NEXP];

    const int tid = threadIdx.x;

    if (tid < 64) smg[tid] = (tid < NCH) ? mg[tid] : -FLT_MAX;
    if (tid >= 64 && tid < 64 + NEXP) {
        const int e = tid - 64;
        sA[e] = escal[e];       sC[e] = escal[22 + e];
        sP[e] = escal[44 + e];  sQ[e] = escal[66 + e];
    }

    const int b0 = blockIdx.x * 4;
    // stage 4 rows of x (945 float4, coalesced) + zero the A image
    {
        const float4* x4 = (const float4*)x + (size_t)blockIdx.x * 945;
        float4* xsh4 = (float4*)xsh;
        float4* ash4 = (float4*)ash;
        const float4 z = make_float4(0.f, 0.f, 0.f, 0.f);
        for (int q = tid; q < 945; q += 256) {
            xsh4[q] = x4[q];
            ash4[q] = z;
        }
    }
    __syncthreads();

    // wave-0 ballot top-22: rank channel t among 45 (ties -> lower index wins)
    if (tid < 64) {
        const float v = smg[tid];
        int rank = 0;
        #pragma unroll
        for (int i = 0; i < NCH; ++i) {
            const float u = smg[i];
            rank += (u > v || (u == v && i < tid)) ? 1 : 0;
        }
        const bool seld = (tid < NCH) && (rank < NEXP);
        const unsigned long long m = __ballot(seld);
        if (seld) {
            const int e = __popcll(m & ((1ull << tid) - 1ull));
            ssel[e] = tid;
        }
    }
    __syncthreads();

    if (tid < 4 * NEXP) {               // gates for 4 batches x 22 selected channels
        const int bi = tid / NEXP, e = tid - bi * NEXP;
        gat[bi][e] = gate[(size_t)(b0 + bi) * NCH + ssel[e]];
    }
    __syncthreads();

    // 4*462 = 1848 row-tasks: softmax over m of alpha*xs[m] (no max-sub: |a*x|<~3)
    for (int t = tid; t < 1848; t += 256) {
        const int bi = t / 462;
        const int r  = t - bi * 462;
        const int e  = r / 21;
        const int l  = r - e * 21;
        const float* xr = &xsh[bi * ROWLEN + ssel[e] * SEQL];
        const float alpha = fmaf(sA[e], xr[l], sC[e]);
        float den = 0.f, num = 0.f;
        #pragma unroll
        for (int mm = 0; mm < SEQL; ++mm) {
            const float wgt = __expf(alpha * xr[mm]);
            den += wgt;
            num = fmaf(xr[mm], wgt, num);
        }
        const float y = fmaf(sP[e], num / den, sQ[e]);
        ash[bi * ROWLEN + ssel[e] * SEQL + l] = y * gat[bi][e];
    }
    __syncthreads();

    // coalesced float4 writes: G = A .* x, then A
    {
        const float4* xsh4 = (const float4*)xsh;
        const float4* ash4 = (const float4*)ash;
        float4* g4 = (float4*)out + (size_t)blockIdx.x * 945;
        float4* a4 = (float4*)(out + (size_t)GOFF) + (size_t)blockIdx.x * 945;
        for (int q = tid; q < 945; q += 256) {
            const float4 a = ash4[q];
            const float4 xv = xsh4[q];
            g4[q] = make_float4(a.x * xv.x, a.y * xv.y, a.z * xv.z, a.w * xv.w);
            a4[q] = a;
        }
    }
}

extern "C" void kernel_launch(void* const* d_in, const int* in_sizes, int n_in,
                              void* d_out, int out_size, void* d_ws, size_t ws_size,
                              hipStream_t stream)
{
    const float* x    = (const float*)d_in[0];
    const float* gc_w = (const float*)d_in[1];
    const float* gc_b = (const float*)d_in[2];
    const float* w1   = (const float*)d_in[3];
    const float* b1   = (const float*)d_in[4];
    const float* w2   = (const float*)d_in[5];
    const float* b2   = (const float*)d_in[6];
    const float* wq   = (const float*)d_in[7];
    const float* bq   = (const float*)d_in[8];
    const float* wk   = (const float*)d_in[9];
    const float* bk   = (const float*)d_in[10];
    const float* wv   = (const float*)d_in[11];
    const float* bv   = (const float*)d_in[12];
    const float* wo   = (const float*)d_in[13];
    const float* bo   = (const float*)d_in[14];

    float* ws        = (float*)d_ws;
    float* gateBuf   = ws;                       // BATCH*45 = 368640 floats
    float* partialsT = ws + 368640;              // 45*1024  = 46080 floats (channel-major)
    float* mg        = ws + 414720;              // 45 floats (pad to 64)
    float* escal     = ws + 414784;              // 88 floats (A,C,P,Q per expert)
    float* outF      = (float*)d_out;

    k1_gate<<<dim3(K1_BLOCKS), dim3(256), 0, stream>>>(x, gc_w, gc_b, w1, b1, w2, b2,
                                                       gateBuf, partialsT);
    k2_reduce<<<dim3(46), dim3(256), 0, stream>>>(partialsT, wq, bq, wk, bk, wv, bv,
                                                  wo, bo, mg, escal);
    k3_attn<<<dim3(K3_BLOCKS), dim3(256), 0, stream>>>(x, gateBuf, mg, escal, outF);
}